// Round 11
// baseline (30.264 us; speedup 1.0000x reference)
//
#include <hip/hip_runtime.h>
#include <math.h>

#define L_OBS   512
#define NSEG    8192
#define NB      8
#define EPS_PAR 1e-4f
#define ANG_STEP 0.012271846644580566f  // 2*pi / 512
#define INV_STEP 81.48733086305042f     // 1/ANG_STEP
#define PI_F     3.14159265358979f
#define TWOPI_F  6.28318530717959f
#define INV_2PI  0.15915494309189535f
#define MARG     2e-3f                  // rad margin >> atan2f error

#define NCHK   16
#define CHKSZ  (NSEG / NCHK)            // 512 segs per chunk

// Single-dispatch raycast: block = (b, 16-beam group), 256 blocks x 1024 threads.
// Thread = (beam bm = t&15, slice = t>>4). Per chunk: threads t<512 wedge-cull
// segs into LDS (capacity == chunk size -> overflow impossible; superset of
// hittable set per R10's proven test, here with a 16-beam arc -> keep ~0.28
// vs R10's 0.5). All 1024 threads then stride the compacted list. Each block
// fully owns its beams: shfl+LDS reduce, outputs written inline. No workspace,
// no second kernel. fmin over the compacted set is order-independent ->
// deterministic despite LDS-append ordering.
__global__ __launch_bounds__(1024) void raycast11_kernel(
    const float4* __restrict__ seg, const float* __restrict__ pose,
    float* __restrict__ out) {
    __shared__ float4 s4[CHKSZ];     // compacted {sx, sy, xd, yd}
    __shared__ float  red[16][16];   // [wave][beam]
    __shared__ int    s_cnt[NCHK];

    const int g   = blockIdx.x;      // 256 = 8b * 32grp
    const int b   = g >> 5;
    const int grp = g & 31;
    const int t   = threadIdx.x;
    const int bm    = t & 15;
    const int slice = t >> 4;        // 0..63
    const int w     = t >> 6;        // 0..15

    const float x1 = pose[b * 3 + 0];
    const float y1 = pose[b * 3 + 1];
    const float th = pose[b * 3 + 2];
    const int   B0 = grp << 4;
    const int   B1 = B0 + 15;

    const int beam = B0 + bm;
    const float ang = (float)beam * ANG_STEP + th;
    const float rx = cosf(ang), ry = sinf(ang);
    const float INF = __builtin_inff();

    if (t < NCHK) s_cnt[t] = 0;
    __syncthreads();

    float umin = INF;
    for (int c = 0; c < NCHK; ++c) {
        if (t < CHKSZ) {
            float4 v = seg[(c << 9) + t];
            float aA = atan2f(v.y - y1, v.x - x1);
            float aB = atan2f(v.w - y1, v.z - x1);
            float d  = aB - aA;
            if (d > PI_F) d -= TWOPI_F; else if (d < -PI_F) d += TWOPI_F;
            float lo  = (d >= 0.0f) ? aA : aB;
            float wdt = fabsf(d);

            bool keep;
            if (wdt > PI_F - 0.02f) {
                keep = true;                 // degenerate / pose near segment line
            } else {
                float a = lo - th;
                a -= floorf(a * INV_2PI) * TWOPI_F;        // [0, 2pi)
                int ilo = (int)floorf((a - MARG) * INV_STEP);
                int ihi = (int)floorf((a + wdt + MARG) * INV_STEP) + 1;
                if (ilo < 0) { ilo += 512; ihi += 512; }
                keep = (ilo <= B1 && ihi >= B0) || (ihi >= B0 + 512);
            }
            if (keep) {
                int pos = atomicAdd(&s_cnt[c], 1);
                s4[pos] = make_float4(v.z - v.x, v.w - v.y, x1 - v.x, y1 - v.y);
            }
        }
        __syncthreads();

        const int n = s_cnt[c];
        for (int i = slice; i < n; i += 64) {
            float4 s = s4[i];                 // {sx, sy, xd, yd}
            float rxs = s.y * rx - s.x * ry;
            float na  = s.x * s.w - s.y * s.z;
            float nb  = rx * s.w - ry * s.z;
            float r   = __builtin_amdgcn_rcpf(rxs);
            float ua  = na * r;
            float ub  = nb * r;
            bool ok = (fabsf(rxs) >= EPS_PAR) & (ub >= 0.0f) & (ub <= 1.0f) & (ua >= 0.0f);
            umin = fminf(umin, ok ? ua : INF);
        }
        __syncthreads();                      // before next stage overwrites s4
    }

    // Reduce 64 slices per beam: shfl over slice bits inside each wave (4
    // slices/wave), then a 16-wave LDS tree handled by the first 16 threads.
    umin = fminf(umin, __shfl_xor(umin, 16));
    umin = fminf(umin, __shfl_xor(umin, 32));
    if ((t & 63) < 16) red[w][bm] = umin;
    __syncthreads();

    if (t < 16) {
        float m = red[0][t];
        #pragma unroll
        for (int j = 1; j < 16; ++j) m = fminf(m, red[j][t]);

        const int gbeam = B0 + t;
        const float angf = (float)gbeam * ANG_STEP + th;
        const float rxf = cosf(angf), ryf = sinf(angf);

        if (isinf(m)) {
            // No valid intersection: ref takes u_a[0] (argmin of all-inf -> idx 0).
            float4 s0 = seg[0];
            float sx = s0.z - s0.x, sy = s0.w - s0.y;
            float xd = x1 - s0.x,   yd = y1 - s0.y;
            float rxs   = sy * rxf - sx * ryf;
            float num_a = sx * yd - sy * xd;
            m = (fabsf(rxs) < EPS_PAR) ? 0.0f : (num_a / rxs);
        }

        float ix = x1 + rxf * m;
        float iy = y1 + ryf * m;
        float dx = ix - x1, dy = iy - y1;
        float c = cosf(th), s = sinf(th);
        const int gb = b * L_OBS + gbeam;
        out[gb * 2 + 0] = ix;
        out[gb * 2 + 1] = iy;
        const int off = NB * L_OBS * 2;
        out[off + gb * 2 + 0] =  dx * c + dy * s;   // R = [[c,-s],[s,c]], out = d @ R
        out[off + gb * 2 + 1] = -dx * s + dy * c;
    }
}

extern "C" void kernel_launch(void* const* d_in, const int* in_sizes, int n_in,
                              void* d_out, int out_size, void* d_ws, size_t ws_size,
                              hipStream_t stream) {
    const float4* seg  = (const float4*)d_in[0];   // (N,4) float32
    const float*  pose = (const float*)d_in[1];    // (B,3) float32
    float* out = (float*)d_out;

    raycast11_kernel<<<NB * 32, 1024, 0, stream>>>(seg, pose, out);
}

// Round 12
// 26.497 us; speedup vs baseline: 1.1422x; 1.1422x over previous
//
#include <hip/hip_runtime.h>
#include <math.h>

#define L_OBS   512
#define NSEG    8192
#define NB      8
#define EPS_PAR 1e-4f
#define ANG_STEP 0.012271846644580566f  // 2*pi / 512

#define NCHK   16
#define CHKSZ  512                      // segs per chunk (= blockDim)

// Single dispatch. Block = (b, 8-beam group): 512 blocks x 512 threads (2/CU).
// Per chunk: every thread wedge-culls ONE segment via cross-product sign tests
// (no atan2), compacts keepers into LDS (capacity == chunk size -> overflow
// impossible; superset of hittable set -> exact min). Inner: thread = (beam
// bm = t&7, slice = t>>3) strides the compacted list. Block fully owns its 8
// beams: shfl/LDS reduce + inline output. No workspace, no second kernel.
// fmin over a permuted set is order-independent -> deterministic.
//
// Cull geometry: ray from P can hit segment AB iff its direction lies in the
// minor cone W between dir(P->A), dir(P->B). Block's beams lie in arc A
// = [d0, d1] (8 beams + 1-step margin each side, width 0.123 rad << pi).
// Overlap(A, W) iff a-in-A | b-in-A | d0-in-W | d1-in-W (both cones < pi),
// tested with 5 cross products; M = 0.25 slack (angle ~ M/|a| >> fp error).
__global__ __launch_bounds__(512) void raycast12_kernel(
    const float4* __restrict__ seg, const float* __restrict__ pose,
    float* __restrict__ out) {
    __shared__ float4 s4[CHKSZ];     // compacted {sx, sy, xd, yd}
    __shared__ float  red[8][8];     // [wave][beam]
    __shared__ int    s_cnt[NCHK];

    const int blk = blockIdx.x;      // 512 = 8b * 64grp
    const int b   = blk >> 6;
    const int grp = blk & 63;
    const int t   = threadIdx.x;
    const int bm    = t & 7;
    const int slice = t >> 3;        // 0..63
    const int w     = t >> 6;        // 0..7

    const float x1 = pose[b * 3 + 0];
    const float y1 = pose[b * 3 + 1];
    const float th = pose[b * 3 + 2];
    const int   B0 = grp << 3;

    // Arc bounds with +-1 beam-step margin
    const float a0 = (float)(B0 - 1) * ANG_STEP + th;
    const float a1 = (float)(B0 + 8) * ANG_STEP + th;
    const float d0x = cosf(a0), d0y = sinf(a0);
    const float d1x = cosf(a1), d1y = sinf(a1);

    const int beam = B0 + bm;
    const float ang = (float)beam * ANG_STEP + th;
    const float rx = cosf(ang), ry = sinf(ang);
    const float INF = __builtin_inff();

    if (t < NCHK) s_cnt[t] = 0;
    __syncthreads();

    float umin = INF;
    for (int c = 0; c < NCHK; ++c) {
        {   // stage+cull: one segment per thread
            float4 v = seg[(c << 9) + t];
            float ax = v.x - x1, ay = v.y - y1;     // dir P->A
            float bx = v.z - x1, by = v.w - y1;     // dir P->B
            float X0a = d0x * ay - d0y * ax;        // cross(d0, a)
            float Xa1 = ax * d1y - ay * d1x;        // cross(a, d1)
            float X0b = d0x * by - d0y * bx;        // cross(d0, b)
            float Xb1 = bx * d1y - by * d1x;        // cross(b, d1)
            float Xab = ax * by - ay * bx;          // cross(a, b)
            const float M = 0.25f;

            bool inA_a = (X0a >= -M) & (Xa1 >= -M);
            bool inA_b = (X0b >= -M) & (Xb1 >= -M);
            bool d0W, d1W;
            if (Xab >= 0.0f) {      // W runs CCW a -> b
                d0W = (X0a <=  M) & (X0b >= -M);
                d1W = (Xa1 >= -M) & (Xb1 <=  M);
            } else {                // W runs CCW b -> a
                d0W = (X0b <=  M) & (X0a >= -M);
                d1W = (Xb1 >= -M) & (Xa1 <=  M);
            }
            float la2 = ax * ax + ay * ay;
            float lb2 = bx * bx + by * by;
            bool degen = (Xab * Xab <= 4e-6f * la2 * lb2);  // P ~ on segment line

            if (inA_a | inA_b | d0W | d1W | degen) {
                int pos = atomicAdd(&s_cnt[c], 1);
                s4[pos] = make_float4(v.z - v.x, v.w - v.y, x1 - v.x, y1 - v.y);
            }
        }
        __syncthreads();

        const int n = s_cnt[c];
        for (int i = slice; i < n; i += 64) {
            float4 s = s4[i];                 // {sx, sy, xd, yd}
            float rxs = s.y * rx - s.x * ry;
            float na  = s.x * s.w - s.y * s.z;
            float nb  = rx * s.w - ry * s.z;
            float r   = __builtin_amdgcn_rcpf(rxs);
            float ua  = na * r;
            float ub  = nb * r;
            bool ok = (fabsf(rxs) >= EPS_PAR) & (ub >= 0.0f) & (ub <= 1.0f) & (ua >= 0.0f);
            umin = fminf(umin, ok ? ua : INF);
        }
        __syncthreads();                      // before next stage overwrites s4
    }

    // Reduce slices: within-wave slice bits are lane bits 3..5, then 8 waves.
    umin = fminf(umin, __shfl_xor(umin, 8));
    umin = fminf(umin, __shfl_xor(umin, 16));
    umin = fminf(umin, __shfl_xor(umin, 32));
    if ((t & 63) < 8) red[w][bm] = umin;
    __syncthreads();

    if (t < 8) {
        float m = red[0][t];
        #pragma unroll
        for (int j = 1; j < 8; ++j) m = fminf(m, red[j][t]);

        const int gbeam = B0 + t;
        const float angf = (float)gbeam * ANG_STEP + th;
        const float rxf = cosf(angf), ryf = sinf(angf);

        if (isinf(m)) {
            // No valid intersection: ref takes u_a[0] (argmin of all-inf -> idx 0).
            float4 s0 = seg[0];
            float sx = s0.z - s0.x, sy = s0.w - s0.y;
            float xd = x1 - s0.x,   yd = y1 - s0.y;
            float rxs   = sy * rxf - sx * ryf;
            float num_a = sx * yd - sy * xd;
            m = (fabsf(rxs) < EPS_PAR) ? 0.0f : (num_a / rxs);
        }

        float ix = x1 + rxf * m;
        float iy = y1 + ryf * m;
        float dx = ix - x1, dy = iy - y1;
        float c = cosf(th), s = sinf(th);
        const int gb = b * L_OBS + gbeam;
        out[gb * 2 + 0] = ix;
        out[gb * 2 + 1] = iy;
        const int off = NB * L_OBS * 2;
        out[off + gb * 2 + 0] =  dx * c + dy * s;   // R = [[c,-s],[s,c]], out = d @ R
        out[off + gb * 2 + 1] = -dx * s + dy * c;
    }
}

extern "C" void kernel_launch(void* const* d_in, const int* in_sizes, int n_in,
                              void* d_out, int out_size, void* d_ws, size_t ws_size,
                              hipStream_t stream) {
    const float4* seg  = (const float4*)d_in[0];   // (N,4) float32
    const float*  pose = (const float*)d_in[1];    // (B,3) float32
    float* out = (float*)d_out;

    raycast12_kernel<<<NB * 64, 512, 0, stream>>>(seg, pose, out);
}

// Round 13
// 18.393 us; speedup vs baseline: 1.6454x; 1.4406x over previous
//
#include <hip/hip_runtime.h>
#include <math.h>

#define L_OBS   512
#define NSEG    8192
#define NB      8
#define EPS_PAR 1e-4f
#define ANG_STEP 0.012271846644580566f  // 2*pi / 512

// Rotation constants: 64*STEP = pi/4 exactly; 129*STEP = 1.58306822 rad.
#define C64   0.70710678118654752f
#define C129  (-0.0122715808f)
#define S129  (0.9999246959f)

#define SC2   32
#define CSEG2 (NSEG / SC2)               // 256 segs per block
#define PART2_FLOATS (SC2 * NB * L_OBS)  // 512 KB

// R10 skeleton: block = (b, beamgroup of 128 beams, segchunk of 256 segs),
// 512 threads (8 waves). Stage-time wedge cull, LDS-compact (capacity == chunk
// -> no overflow; superset of hittable set -> exact min). Wave w strides the
// compacted list by 8; thread owns beams (bg*128+lane, +64).
// R13 changes vs R10: (1) cull via cross-product sign tests (field-proven in
// R12, bit-identical absmax) instead of 2x atan2f; (2) second beam dir and
// arc-end dir via exact rotation identities instead of extra sincos.
__global__ __launch_bounds__(512) void raycast13_kernel(
    const float4* __restrict__ seg, const float* __restrict__ pose,
    float* __restrict__ part) {
    __shared__ float4 s4[CSEG2];     // compacted {sx, sy, xd, yd}
    __shared__ float  s_red[8][128];
    __shared__ int    s_n;

    const int gid = blockIdx.x;      // 1024 = 8b * 4bg * 32sc
    const int sc = gid & (SC2 - 1);
    const int bg = (gid >> 5) & 3;
    const int b  = gid >> 7;

    const float x1 = pose[b * 3 + 0];
    const float y1 = pose[b * 3 + 1];
    const float th = pose[b * 3 + 2];

    const int t = threadIdx.x;
    if (t == 0) s_n = 0;
    __syncthreads();

    const int lane = t & 63;
    const int w    = t >> 6;         // 0..7
    const int B0   = bg * 128;

    // This thread's two beam dirs: sincos once, second via rotation by pi/4.
    const int beam0 = B0 + lane;
    const float a0 = (float)beam0 * ANG_STEP + th;
    const float rx0 = cosf(a0), ry0 = sinf(a0);
    const float rx1 = C64 * (rx0 - ry0);
    const float ry1 = C64 * (rx0 + ry0);

    if (t < CSEG2) {
        // Arc bounds with +-1 beam-step margin: d0 at (B0-1), d1 at (B0+128).
        const float aa = (float)(B0 - 1) * ANG_STEP + th;
        const float d0x = cosf(aa), d0y = sinf(aa);
        const float d1x = d0x * C129 - d0y * S129;
        const float d1y = d0x * S129 + d0y * C129;

        float4 v = seg[sc * CSEG2 + t];
        float ax = v.x - x1, ay = v.y - y1;     // dir P->A
        float bx = v.z - x1, by = v.w - y1;     // dir P->B
        float X0a = d0x * ay - d0y * ax;        // cross(d0, a)
        float Xa1 = ax * d1y - ay * d1x;        // cross(a, d1)
        float X0b = d0x * by - d0y * bx;        // cross(d0, b)
        float Xb1 = bx * d1y - by * d1x;        // cross(b, d1)
        float Xab = ax * by - ay * bx;          // cross(a, b)
        const float M = 0.25f;

        bool inA_a = (X0a >= -M) & (Xa1 >= -M);
        bool inA_b = (X0b >= -M) & (Xb1 >= -M);
        bool d0W, d1W;
        if (Xab >= 0.0f) {      // wedge runs CCW a -> b
            d0W = (X0a <=  M) & (X0b >= -M);
            d1W = (Xa1 >= -M) & (Xb1 <=  M);
        } else {                // wedge runs CCW b -> a
            d0W = (X0b <=  M) & (X0a >= -M);
            d1W = (Xb1 >= -M) & (Xa1 <=  M);
        }
        float la2 = ax * ax + ay * ay;
        float lb2 = bx * bx + by * by;
        bool degen = (Xab * Xab <= 4e-6f * la2 * lb2);  // P ~ on segment line

        if (inA_a | inA_b | d0W | d1W | degen) {
            int pos = atomicAdd(&s_n, 1);
            s4[pos] = make_float4(bx - ax, by - ay, -ax, -ay);  // {sx, sy, xd, yd}
        }
    }

    const float INF = __builtin_inff();
    __syncthreads();

    const int n = s_n;
    float u0 = INF, u1 = INF;
    #pragma unroll 4
    for (int i = w; i < n; i += 8) {
        float4 s = s4[i];                 // wave-uniform broadcast b128
        float na = s.x * s.w - s.y * s.z; // sx*yd - sy*xd (beam-independent)

        float rxs0 = s.y * rx0 - s.x * ry0;
        float nb0  = rx0 * s.w - ry0 * s.z;
        float r0   = __builtin_amdgcn_rcpf(rxs0);
        float ua0  = na  * r0;
        float ub0  = nb0 * r0;
        bool ok0 = (fabsf(rxs0) >= EPS_PAR) & (ub0 >= 0.0f) & (ub0 <= 1.0f) & (ua0 >= 0.0f);
        u0 = fminf(u0, ok0 ? ua0 : INF);

        float rxs1 = s.y * rx1 - s.x * ry1;
        float nb1  = rx1 * s.w - ry1 * s.z;
        float r1   = __builtin_amdgcn_rcpf(rxs1);
        float ua1  = na  * r1;
        float ub1  = nb1 * r1;
        bool ok1 = (fabsf(rxs1) >= EPS_PAR) & (ub1 >= 0.0f) & (ub1 <= 1.0f) & (ua1 >= 0.0f);
        u1 = fminf(u1, ok1 ? ua1 : INF);
    }

    s_red[w][lane]      = u0;
    s_red[w][lane + 64] = u1;
    __syncthreads();
    if (t < 128) {
        float m0 = fminf(fminf(s_red[0][t], s_red[1][t]),
                         fminf(s_red[2][t], s_red[3][t]));
        float m1 = fminf(fminf(s_red[4][t], s_red[5][t]),
                         fminf(s_red[6][t], s_red[7][t]));
        part[sc * (NB * L_OBS) + b * L_OBS + B0 + t] = fminf(m0, m1);
    }
}

// Parallel finalize (unchanged from R7/R10): 64 blocks x 256 threads.
__global__ __launch_bounds__(256) void finalize7_kernel(
    const float4* __restrict__ seg, const float* __restrict__ pose,
    const float* __restrict__ part, float* __restrict__ out) {
    __shared__ float s_red[4][64];

    const int t    = threadIdx.x;
    const int lane = t & 63;
    const int q    = t >> 6;
    const int gbeam = blockIdx.x * 64 + lane;   // 64 blocks cover 4096 beam-slots

    float u = INFINITY;
    #pragma unroll
    for (int j = 0; j < 8; ++j)
        u = fminf(u, part[(q * 8 + j) * (NB * L_OBS) + gbeam]);

    s_red[q][lane] = u;
    __syncthreads();
    if (t < 64) {
        const int gb   = blockIdx.x * 64 + t;
        const int b    = gb >> 9;
        const int beam = gb & (L_OBS - 1);
        const float x1 = pose[b * 3 + 0];
        const float y1 = pose[b * 3 + 1];
        const float th = pose[b * 3 + 2];
        const float ang = (float)beam * ANG_STEP + th;
        const float rx = cosf(ang), ry = sinf(ang);

        float m = fminf(fminf(s_red[0][t], s_red[1][t]),
                        fminf(s_red[2][t], s_red[3][t]));

        if (isinf(m)) {
            // No valid intersection: ref takes u_a[0] (argmin of all-inf -> idx 0).
            float4 s0 = seg[0];
            float sx = s0.z - s0.x, sy = s0.w - s0.y;
            float xd = x1 - s0.x,   yd = y1 - s0.y;
            float rxs   = sy * rx - sx * ry;
            float num_a = sx * yd - sy * xd;
            m = (fabsf(rxs) < EPS_PAR) ? 0.0f : (num_a / rxs);
        }

        float ix = x1 + rx * m;
        float iy = y1 + ry * m;
        float dx = ix - x1, dy = iy - y1;
        float c = cosf(th), s = sinf(th);
        out[gb * 2 + 0] = ix;
        out[gb * 2 + 1] = iy;
        const int off = NB * L_OBS * 2;
        out[off + gb * 2 + 0] =  dx * c + dy * s;   // R = [[c,-s],[s,c]], out = d @ R
        out[off + gb * 2 + 1] = -dx * s + dy * c;
    }
}

extern "C" void kernel_launch(void* const* d_in, const int* in_sizes, int n_in,
                              void* d_out, int out_size, void* d_ws, size_t ws_size,
                              hipStream_t stream) {
    const float4* seg  = (const float4*)d_in[0];   // (N,4) float32
    const float*  pose = (const float*)d_in[1];    // (B,3) float32
    float* out = (float*)d_out;
    float* part = (float*)d_ws;                    // [SC2][NB*L_OBS], 512 KB

    raycast13_kernel<<<1024, 512, 0, stream>>>(seg, pose, part);
    finalize7_kernel<<<64, 256, 0, stream>>>(seg, pose, part, out);
}